// Round 3
// baseline (341.301 us; speedup 1.0000x reference)
//
#include <hip/hip_runtime.h>
#include <hip/hip_bf16.h>
#include <cstdint>

#define HW 256
#define CH 64

typedef __attribute__((ext_vector_type(8))) short bf16x8;
typedef __attribute__((ext_vector_type(4))) float f32x4;

__device__ __forceinline__ float b2f(unsigned short u) {
    union { unsigned int i; float f; } c; c.i = ((unsigned int)u) << 16; return c.f;
}

__device__ __forceinline__ void gload16(const void* g, void* l) {
    __builtin_amdgcn_global_load_lds(
        (const __attribute__((address_space(1))) void*)g,
        (__attribute__((address_space(3))) void*)l, 16, 0, 0);
}

// ---------------------------------------------------------------------------
// Kernel W: conv_w [co][ci][ky][kx] f32 -> wt[ky][kx][co][ci] bf16, with
// 16B-chunk XOR swizzle within each co-row: chunk j stored at j ^ (co&7).
// ---------------------------------------------------------------------------
__global__ void wt_kernel(const float* __restrict__ cw, unsigned short* __restrict__ wt) {
    int i = blockIdx.x * 256 + threadIdx.x;
    if (i >= 9 * 64 * 64) return;
    int e = i & 7, j = (i >> 3) & 7, co = (i >> 6) & 63, t9 = i >> 12;
    int ky = t9 / 3, kx = t9 - ky * 3;
    int ci = j * 8 + e;
    float v = cw[co * 576 + ci * 9 + ky * 3 + kx];
    __hip_bfloat16 h = __float2bfloat16(v);
    wt[t9 * 4096 + co * 64 + ((j ^ (co & 7)) * 8) + e] = *(unsigned short*)&h;
}

// ---------------------------------------------------------------------------
// Kernel A: fused offset conv + tanh + bilinear warp, single-read of x.
// Key fact: |offset| < 2 px, so all bilinear taps for a 16x16 pixel tile lie
// inside its 20x20 halo tile. Stage x tile ONCE: fp32 transient (8-ci groups,
// feeds offset conv at full precision) + bf16 persistent (feeds gather).
// block 16x16 threads; grid (16,16,B). LDS ~72KB -> 2 blocks/CU.
// Output: warped bf16 NHWC [b][y][x][ci], 16B chunk j stored at j^(x&7).
// ---------------------------------------------------------------------------
__global__ __launch_bounds__(256, 2) void offset_warp_kernel(
    const float* __restrict__ x, const float* __restrict__ ow,
    const float* __restrict__ ob, unsigned short* __restrict__ warped)
{
    __shared__ float swt[2 * CH * 9];                 // offset conv weights (4.6 KB)
    __shared__ float sg[8][20][21];                   // fp32 staging, 8 ci (13.4 KB)
    __shared__ unsigned short sxb[CH][20][21];        // bf16 gather tile (53.8 KB)

    const int b = blockIdx.z;
    const int tx = threadIdx.x, ty = threadIdx.y;
    const int t = ty * 16 + tx;
    const int x0 = blockIdx.x * 16, y0 = blockIdx.y * 16;
    const int px = x0 + tx, py = y0 + ty;

    for (int i = t; i < 2 * CH * 9; i += 256) swt[i] = ow[i];

    float acc0 = ob[0], acc1 = ob[1];
    const float* xb = x + (size_t)b * CH * HW * HW;

    for (int g = 0; g < 8; ++g) {
        __syncthreads();   // sg free to overwrite (also covers swt before first read)
        for (int i = t; i < 8 * 20 * 20; i += 256) {
            int ci8 = i / 400;
            int rem = i - ci8 * 400;
            int ly = rem / 20, lx = rem - ly * 20;
            int gy = y0 + ly - 2, gx = x0 + lx - 2;
            float v = 0.f;
            if ((unsigned)gy < HW && (unsigned)gx < HW)
                v = xb[((size_t)(g * 8 + ci8) * HW + gy) * HW + gx];
            sg[ci8][ly][lx] = v;
            __hip_bfloat16 h = __float2bfloat16(v);
            sxb[g * 8 + ci8][ly][lx] = *(unsigned short*)&h;
        }
        __syncthreads();
        #pragma unroll
        for (int ci8 = 0; ci8 < 8; ++ci8) {
            int ci = g * 8 + ci8;
            const float* w0 = &swt[ci * 9];
            const float* w1 = &swt[(CH + ci) * 9];
            #pragma unroll
            for (int ky = 0; ky < 3; ++ky)
                #pragma unroll
                for (int kx = 0; kx < 3; ++kx) {
                    float v = sg[ci8][ty + 1 + ky][tx + 1 + kx];
                    acc0 = fmaf(v, w0[ky * 3 + kx], acc0);
                    acc1 = fmaf(v, w1[ky * 3 + kx], acc1);
                }
        }
    }
    // sxb fully written before the last staging barrier; safe to gather now.

    float off0 = tanhf(acc0) * 2.0f;
    float off1 = tanhf(acc1) * 2.0f;
    float ix = fminf(fmaxf((float)px + off0, 0.f), (float)(HW - 1));
    float iy = fminf(fmaxf((float)py + off1, 0.f), (float)(HW - 1));
    float fx0 = floorf(ix), fy0 = floorf(iy);
    float wx = ix - fx0, wy = iy - fy0;
    int x0i = (int)fx0, y0i = (int)fy0;
    int x1i = min(x0i + 1, HW - 1), y1i = min(y0i + 1, HW - 1);
    // local tile coords (halo 2): always in [0,20)
    int lx0 = x0i - x0 + 2, lx1 = x1i - x0 + 2;
    int ly0 = y0i - y0 + 2, ly1 = y1i - y0 + 2;
    float w00 = (1.f - wx) * (1.f - wy), w01 = wx * (1.f - wy);
    float w10 = (1.f - wx) * wy,         w11 = wx * wy;

    int o00 = ly0 * 21 + lx0, o01 = ly0 * 21 + lx1;
    int o10 = ly1 * 21 + lx0, o11 = ly1 * 21 + lx1;
    const unsigned short* sflat = &sxb[0][0][0];

    unsigned short* wb = warped + ((size_t)b * (HW * HW) + (size_t)py * HW + px) * CH;
    const int key = px & 7;
    #pragma unroll
    for (int j = 0; j < 8; ++j) {
        unsigned int pk[4];
        #pragma unroll
        for (int p = 0; p < 4; ++p) {
            unsigned int pw = 0;
            #pragma unroll
            for (int h = 0; h < 2; ++h) {
                int ci = j * 8 + p * 2 + h;
                const unsigned short* cb = sflat + ci * (20 * 21);
                float v = b2f(cb[o00]) * w00 + b2f(cb[o01]) * w01 +
                          b2f(cb[o10]) * w10 + b2f(cb[o11]) * w11;
                __hip_bfloat16 hh = __float2bfloat16(v);
                pw |= ((unsigned int)*(unsigned short*)&hh) << (16 * h);
            }
            pk[p] = pw;
        }
        uint4 q; q.x = pk[0]; q.y = pk[1]; q.z = pk[2]; q.w = pk[3];
        *(uint4*)&wb[(size_t)((j ^ key) * 8)] = q;
    }
}

// ---------------------------------------------------------------------------
// Kernel B: dilated(12) 3x3 conv 64->64 + BN + ReLU via bf16 MFMA implicit GEMM
// block = 256 threads (4 waves), computes 64co x 256px (one full output row).
// grid (256 oy, 8 b)
// ---------------------------------------------------------------------------
__global__ __launch_bounds__(256, 2) void conv_mfma_kernel(
    const unsigned short* __restrict__ warped, const unsigned short* __restrict__ wtb,
    const float* __restrict__ gamma, const float* __restrict__ beta,
    const float* __restrict__ mean, const float* __restrict__ var,
    float* __restrict__ out)
{
    __shared__ __align__(16) unsigned short sa[280 * 64];    // act row + 12px halos
    __shared__ __align__(16) unsigned short sw[3 * 64 * 64]; // weights for one ky
    __shared__ float sinv[64], sbias[64];

    const int t = threadIdx.x;
    const int oy = blockIdx.x, b = blockIdx.y;
    const int wid = t >> 6, lane = t & 63;
    const int l15 = lane & 15, l4 = lane >> 4;

    if (t < 64) {
        float inv = gamma[t] * rsqrtf(var[t] + 1e-5f);
        sinv[t] = inv;
        sbias[t] = beta[t] - mean[t] * inv;
    }
    if (t < 192) {
        int p = t >> 3, sub = t & 7;
        int px = (p < 12) ? p : (256 + p);
        *(uint4*)&sa[px * 64 + sub * 8] = make_uint4(0, 0, 0, 0);
    }

    f32x4 acc[4][4];
    #pragma unroll
    for (int m = 0; m < 4; ++m)
        #pragma unroll
        for (int n = 0; n < 4; ++n) acc[m][n] = (f32x4){0.f, 0.f, 0.f, 0.f};

    const size_t bbase = (size_t)b * (HW * (size_t)HW * CH);

    for (int ky = 0; ky < 3; ++ky) {
        __syncthreads();
        int gy = oy + (ky - 1) * 12;
        if (gy >= 0 && gy < HW) {
            const char* src = (const char*)(warped + bbase + (size_t)gy * (HW * CH));
            #pragma unroll
            for (int r = 0; r < 8; ++r)
                gload16(src + r * 4096 + t * 16,
                        (char*)sa + 1536 + r * 4096 + wid * 1024);
        } else {
            #pragma unroll
            for (int r = 0; r < 8; ++r)
                *(uint4*)((char*)sa + 1536 + r * 4096 + t * 16) = make_uint4(0, 0, 0, 0);
        }
        {
            const char* wsrc = (const char*)wtb + ky * 24576;
            #pragma unroll
            for (int r = 0; r < 6; ++r)
                gload16(wsrc + r * 4096 + t * 16,
                        (char*)sw + r * 4096 + wid * 1024);
        }
        asm volatile("s_waitcnt vmcnt(0)" ::: "memory");
        __syncthreads();

        #pragma unroll
        for (int kx = 0; kx < 3; ++kx) {
            #pragma unroll
            for (int ks = 0; ks < 2; ++ks) {
                const int jg = ks * 4 + l4;
                bf16x8 af[4], bfr[4];
                #pragma unroll
                for (int m = 0; m < 4; ++m) {
                    int co = m * 16 + l15;
                    int jp = jg ^ (co & 7);
                    af[m] = *(const bf16x8*)&sw[(kx * 64 + co) * 64 + jp * 8];
                }
                #pragma unroll
                for (int n = 0; n < 4; ++n) {
                    int pl = wid * 64 + n * 16 + l15 + kx * 12;
                    int c = jg ^ ((pl + 4) & 7);
                    bfr[n] = *(const bf16x8*)&sa[pl * 64 + c * 8];
                }
                #pragma unroll
                for (int m = 0; m < 4; ++m)
                    #pragma unroll
                    for (int n = 0; n < 4; ++n)
                        acc[m][n] = __builtin_amdgcn_mfma_f32_16x16x32_bf16(
                            af[m], bfr[n], acc[m][n], 0, 0, 0);
            }
        }
    }

    #pragma unroll
    for (int m = 0; m < 4; ++m) {
        #pragma unroll
        for (int r = 0; r < 4; ++r) {
            int co = m * 16 + l4 * 4 + r;
            float inv = sinv[co], bs = sbias[co];
            float* orow = out + (((size_t)b * CH + co) * HW + oy) * HW + wid * 64 + l15;
            #pragma unroll
            for (int n = 0; n < 4; ++n)
                orow[n * 16] = fmaxf(fmaf(acc[m][n][r], inv, bs), 0.f);
        }
    }
}

extern "C" void kernel_launch(void* const* d_in, const int* in_sizes, int n_in,
                              void* d_out, int out_size, void* d_ws, size_t ws_size,
                              hipStream_t stream) {
    const float* x     = (const float*)d_in[0];
    const float* ow    = (const float*)d_in[1];
    const float* ob    = (const float*)d_in[2];
    const float* cw    = (const float*)d_in[3];
    const float* gamma = (const float*)d_in[4];
    const float* beta  = (const float*)d_in[5];
    const float* mean  = (const float*)d_in[6];
    const float* var   = (const float*)d_in[7];
    float* out = (float*)d_out;

    unsigned short* warped = (unsigned short*)d_ws;  // 64 MB NHWC bf16 (swizzled)
    unsigned short* wtb    = (unsigned short*)((char*)d_ws + (size_t)8 * CH * HW * HW * 2);

    wt_kernel<<<(9 * 64 * 64 + 255) / 256, 256, 0, stream>>>(cw, wtb);

    dim3 bA(16, 16);
    dim3 gA(16, 16, 8);
    offset_warp_kernel<<<gA, bA, 0, stream>>>(x, ow, ob, warped);

    conv_mfma_kernel<<<dim3(HW, 8), 256, 0, stream>>>(warped, wtb, gamma, beta, mean, var, out);
}

// Round 4
// 201.845 us; speedup vs baseline: 1.6909x; 1.6909x over previous
//
#include <hip/hip_runtime.h>
#include <hip/hip_bf16.h>
#include <cstdint>

#define HW 256
#define CH 64

typedef __attribute__((ext_vector_type(8))) short bf16x8;
typedef __attribute__((ext_vector_type(4))) float f32x4;

__device__ __forceinline__ float b2f(unsigned short u) {
    union { unsigned int i; float f; } c; c.i = ((unsigned int)u) << 16; return c.f;
}

__device__ __forceinline__ void gload16(const void* g, void* l) {
    __builtin_amdgcn_global_load_lds(
        (const __attribute__((address_space(1))) void*)g,
        (__attribute__((address_space(3))) void*)l, 16, 0, 0);
}

// ---------------------------------------------------------------------------
// Kernel W: conv_w [co][ci][ky][kx] f32 -> wt[ky][kx][co][ci] bf16, with
// 16B-chunk XOR swizzle within each co-row: chunk j stored at j ^ (co&7).
// ---------------------------------------------------------------------------
__global__ void wt_kernel(const float* __restrict__ cw, unsigned short* __restrict__ wt) {
    int i = blockIdx.x * 256 + threadIdx.x;
    if (i >= 9 * 64 * 64) return;
    int e = i & 7, j = (i >> 3) & 7, co = (i >> 6) & 63, t9 = i >> 12;
    int ky = t9 / 3, kx = t9 - ky * 3;
    int ci = j * 8 + e;
    float v = cw[co * 576 + ci * 9 + ky * 3 + kx];
    __hip_bfloat16 h = __float2bfloat16(v);
    wt[t9 * 4096 + co * 64 + ((j ^ (co & 7)) * 8) + e] = *(unsigned short*)&h;
}

// ---------------------------------------------------------------------------
// Kernel A: fused offset conv + tanh + bilinear warp.
// Single bf16 LDS tile [64ci][20][20] (halo 2: |offset|<2). ~50KB -> 3 blk/CU.
// ONE barrier: stage everything (float2 loads, independent) -> sync ->
// conv (merged u32-pair LDS reads, s_load weights) -> tanh -> gather -> store.
// Offset-conv on bf16 inputs: offset err ~4e-3 px -> warped err ~6e-3, OK.
// grid 2048 (XCD-chunked: each XCD = one batch image).
// Output: warped bf16 NHWC [b][y][x][ci], 16B chunk j stored at j^(x&7).
// ---------------------------------------------------------------------------
__global__ __launch_bounds__(256, 3) void offset_warp_kernel(
    const float* __restrict__ x, const float* __restrict__ ow,
    const float* __restrict__ ob, unsigned short* __restrict__ warped)
{
    __shared__ unsigned short sxb[64 * 400 + 24];   // [ci][ly][lx], +pad for pair-read overrun

    // XCD-chunked remap: 2048 blocks, 8 XCDs -> XCD k owns batch k (256 tiles)
    const int orig = blockIdx.x;
    const int lid = (orig & 7) * 256 + (orig >> 3);
    const int bx = lid & 15, by = (lid >> 4) & 15, b = lid >> 8;

    const int t = threadIdx.x;
    const int tx = t & 15, ty = t >> 4;
    const int x0 = bx * 16, y0 = by * 16;
    const int px = x0 + tx, py = y0 + ty;
    const float* xb = x + (size_t)b * CH * HW * HW;

    // ---- stage: 64ci x 20 rows x 10 float2 = 12800 words, 50 iters/thread
    unsigned int* S32 = (unsigned int*)sxb;
    for (int i = t; i < 12800; i += 256) {
        int c2 = i % 10;
        int r  = i / 10;           // ci*20 + ly
        int ly = r % 20;
        int ci = r / 20;
        int gy = y0 + ly - 2;
        int gx = x0 + (c2 << 1) - 2;   // even, so gx+1<=255 iff gx<256
        unsigned int pk = 0;
        if ((unsigned)gy < HW && (unsigned)gx < HW) {
            float2 v = *(const float2*)&xb[((size_t)ci * HW + gy) * HW + gx];
            __hip_bfloat16 h0 = __float2bfloat16(v.x);
            __hip_bfloat16 h1 = __float2bfloat16(v.y);
            pk = (unsigned int)*(unsigned short*)&h0 |
                 ((unsigned int)*(unsigned short*)&h1 << 16);
        }
        S32[ci * 200 + ly * 10 + c2] = pk;
    }
    __syncthreads();

    // ---- offset conv: taps at lx = tx+1+kx read via 2 adjacent u32 + shift
    const unsigned int* S = (const unsigned int*)sxb;
    const int shc = ((tx + 1) & 1) * 16;
    float acc0 = ob[0], acc1 = ob[1];
    for (int ci = 0; ci < CH; ++ci) {
        const float* w0 = &ow[ci * 9];          // wave-uniform -> s_load
        const float* w1 = &ow[(CH + ci) * 9];
        const int base = ci * 200;
        #pragma unroll
        for (int ky = 0; ky < 3; ++ky) {
            int s = (ty + 1 + ky) * 20 + tx + 1;
            int w = base + (s >> 1);
            unsigned long long u =
                ((unsigned long long)S[w + 1] << 32) | (unsigned long long)S[w];
            u >>= shc;
            float t0 = b2f((unsigned short)u);
            float t1 = b2f((unsigned short)(u >> 16));
            float t2 = b2f((unsigned short)(u >> 32));
            acc0 = fmaf(t0, w0[ky * 3 + 0], acc0);
            acc1 = fmaf(t0, w1[ky * 3 + 0], acc1);
            acc0 = fmaf(t1, w0[ky * 3 + 1], acc0);
            acc1 = fmaf(t1, w1[ky * 3 + 1], acc1);
            acc0 = fmaf(t2, w0[ky * 3 + 2], acc0);
            acc1 = fmaf(t2, w1[ky * 3 + 2], acc1);
        }
    }

    // ---- positions
    float off0 = tanhf(acc0) * 2.0f;
    float off1 = tanhf(acc1) * 2.0f;
    float ix = fminf(fmaxf((float)px + off0, 0.f), 255.f);
    float iy = fminf(fmaxf((float)py + off1, 0.f), 255.f);
    float fx0 = floorf(ix), fy0 = floorf(iy);
    float wx = ix - fx0, wy = iy - fy0;
    int lx0 = (int)fx0 - x0 + 2;       // in [0,18] (19 only in tanh==1 edge, weight 0)
    int ly0 = (int)fy0 - y0 + 2;
    float w00 = (1.f - wx) * (1.f - wy), w01 = wx * (1.f - wy);
    float w10 = (1.f - wx) * wy,         w11 = wx * wy;
    // pair-read: v01 = next short (weight 0 whenever the true x1i != x0i+1);
    // v10/v11 = next row (staged, zero-filled or weight-0 at edges).
    const int offw = ly0 * 20 + lx0;
    const int w0i = offw >> 1;
    const int shg = (offw & 1) * 16;

    // ---- gather + pack + swizzled NHWC store
    unsigned short* wb = warped + ((size_t)b * (HW * HW) + (size_t)py * HW + px) * CH;
    const int key = px & 7;
    #pragma unroll
    for (int j = 0; j < 8; ++j) {
        unsigned int pk[4];
        #pragma unroll
        for (int p = 0; p < 4; ++p) {
            unsigned int pw = 0;
            #pragma unroll
            for (int h = 0; h < 2; ++h) {
                int ci = j * 8 + p * 2 + h;
                int bw = ci * 200 + w0i;
                unsigned long long ra =
                    ((unsigned long long)S[bw + 1] << 32) | (unsigned long long)S[bw];
                ra >>= shg;
                unsigned long long rb =
                    ((unsigned long long)S[bw + 11] << 32) | (unsigned long long)S[bw + 10];
                rb >>= shg;
                float v = b2f((unsigned short)ra) * w00 +
                          b2f((unsigned short)(ra >> 16)) * w01 +
                          b2f((unsigned short)rb) * w10 +
                          b2f((unsigned short)(rb >> 16)) * w11;
                __hip_bfloat16 hh = __float2bfloat16(v);
                pw |= ((unsigned int)*(unsigned short*)&hh) << (16 * h);
            }
            pk[p] = pw;
        }
        uint4 q; q.x = pk[0]; q.y = pk[1]; q.z = pk[2]; q.w = pk[3];
        *(uint4*)&wb[(size_t)((j ^ key) * 8)] = q;
    }
}

// ---------------------------------------------------------------------------
// Kernel B: dilated(12) 3x3 conv 64->64 + BN + ReLU via bf16 MFMA implicit GEMM
// block = 256 threads (4 waves), computes 64co x 256px (one full output row).
// grid 2048 (XCD-chunked: XCD k = batch k -> oy,oy±12 rows reuse in its L2)
// ---------------------------------------------------------------------------
__global__ __launch_bounds__(256, 2) void conv_mfma_kernel(
    const unsigned short* __restrict__ warped, const unsigned short* __restrict__ wtb,
    const float* __restrict__ gamma, const float* __restrict__ beta,
    const float* __restrict__ mean, const float* __restrict__ var,
    float* __restrict__ out)
{
    __shared__ __align__(16) unsigned short sa[280 * 64];    // act row + 12px halos
    __shared__ __align__(16) unsigned short sw[3 * 64 * 64]; // weights for one ky
    __shared__ float sinv[64], sbias[64];

    const int t = threadIdx.x;
    const int orig = blockIdx.x;
    const int lid = (orig & 7) * 256 + (orig >> 3);
    const int oy = lid & 255, b = lid >> 8;
    const int wid = t >> 6, lane = t & 63;
    const int l15 = lane & 15, l4 = lane >> 4;

    if (t < 64) {
        float inv = gamma[t] * rsqrtf(var[t] + 1e-5f);
        sinv[t] = inv;
        sbias[t] = beta[t] - mean[t] * inv;
    }
    if (t < 192) {
        int p = t >> 3, sub = t & 7;
        int px = (p < 12) ? p : (256 + p);
        *(uint4*)&sa[px * 64 + sub * 8] = make_uint4(0, 0, 0, 0);
    }

    f32x4 acc[4][4];
    #pragma unroll
    for (int m = 0; m < 4; ++m)
        #pragma unroll
        for (int n = 0; n < 4; ++n) acc[m][n] = (f32x4){0.f, 0.f, 0.f, 0.f};

    const size_t bbase = (size_t)b * (HW * (size_t)HW * CH);

    for (int ky = 0; ky < 3; ++ky) {
        __syncthreads();
        int gy = oy + (ky - 1) * 12;
        if (gy >= 0 && gy < HW) {
            const char* src = (const char*)(warped + bbase + (size_t)gy * (HW * CH));
            #pragma unroll
            for (int r = 0; r < 8; ++r)
                gload16(src + r * 4096 + t * 16,
                        (char*)sa + 1536 + r * 4096 + wid * 1024);
        } else {
            #pragma unroll
            for (int r = 0; r < 8; ++r)
                *(uint4*)((char*)sa + 1536 + r * 4096 + t * 16) = make_uint4(0, 0, 0, 0);
        }
        {
            const char* wsrc = (const char*)wtb + ky * 24576;
            #pragma unroll
            for (int r = 0; r < 6; ++r)
                gload16(wsrc + r * 4096 + t * 16,
                        (char*)sw + r * 4096 + wid * 1024);
        }
        asm volatile("s_waitcnt vmcnt(0)" ::: "memory");
        __syncthreads();

        #pragma unroll
        for (int kx = 0; kx < 3; ++kx) {
            #pragma unroll
            for (int ks = 0; ks < 2; ++ks) {
                const int jg = ks * 4 + l4;
                bf16x8 af[4], bfr[4];
                #pragma unroll
                for (int m = 0; m < 4; ++m) {
                    int co = m * 16 + l15;
                    int jp = jg ^ (co & 7);
                    af[m] = *(const bf16x8*)&sw[(kx * 64 + co) * 64 + jp * 8];
                }
                #pragma unroll
                for (int n = 0; n < 4; ++n) {
                    int pl = wid * 64 + n * 16 + l15 + kx * 12;
                    int c = jg ^ ((pl + 4) & 7);
                    bfr[n] = *(const bf16x8*)&sa[pl * 64 + c * 8];
                }
                #pragma unroll
                for (int m = 0; m < 4; ++m)
                    #pragma unroll
                    for (int n = 0; n < 4; ++n)
                        acc[m][n] = __builtin_amdgcn_mfma_f32_16x16x32_bf16(
                            af[m], bfr[n], acc[m][n], 0, 0, 0);
            }
        }
    }

    #pragma unroll
    for (int m = 0; m < 4; ++m) {
        #pragma unroll
        for (int r = 0; r < 4; ++r) {
            int co = m * 16 + l4 * 4 + r;
            float inv = sinv[co], bs = sbias[co];
            float* orow = out + (((size_t)b * CH + co) * HW + oy) * HW + wid * 64 + l15;
            #pragma unroll
            for (int n = 0; n < 4; ++n)
                orow[n * 16] = fmaxf(fmaf(acc[m][n][r], inv, bs), 0.f);
        }
    }
}

extern "C" void kernel_launch(void* const* d_in, const int* in_sizes, int n_in,
                              void* d_out, int out_size, void* d_ws, size_t ws_size,
                              hipStream_t stream) {
    const float* x     = (const float*)d_in[0];
    const float* ow    = (const float*)d_in[1];
    const float* ob    = (const float*)d_in[2];
    const float* cw    = (const float*)d_in[3];
    const float* gamma = (const float*)d_in[4];
    const float* beta  = (const float*)d_in[5];
    const float* mean  = (const float*)d_in[6];
    const float* var   = (const float*)d_in[7];
    float* out = (float*)d_out;

    unsigned short* warped = (unsigned short*)d_ws;  // 64 MB NHWC bf16 (swizzled)
    unsigned short* wtb    = (unsigned short*)((char*)d_ws + (size_t)8 * CH * HW * HW * 2);

    wt_kernel<<<(9 * 64 * 64 + 255) / 256, 256, 0, stream>>>(cw, wtb);

    offset_warp_kernel<<<dim3(2048), 256, 0, stream>>>(x, ow, ob, warped);

    conv_mfma_kernel<<<dim3(2048), 256, 0, stream>>>(warped, wtb, gamma, beta, mean, var, out);
}